// Round 4
// baseline (91.528 us; speedup 1.0000x reference)
//
#include <hip/hip_runtime.h>
#include <hip/hip_bf16.h>

// Problem: B=4096, IN=1024, H=1024.
// pre = x@U^T + h@W^T + Ub -> gates -> h_t, c_t   (fused after convert)
// GEMM: M=4096 (batch), N=4096 (4H permuted), K=2048 (IN+H concat)
//
// B-permutation: permuted column p = bn*256 + wn*64 + g*16 + c corresponds to
// gate g (f,i,o,g), hidden j = bn*64 + wn*16 + c. With the verified C/D
// layout (col = lane&15), wave fragment n == gate n at the SAME lane (same j),
// so the LSTM gate math is lane-local in the GEMM epilogue.

#define BATCH 4096
#define HID   1024
#define KDIM  2048

// 256x256 tile, BK=32, 4-slot LDS ring, 8 waves (2Mx4N), 512 threads.
#define BM 256
#define BN 256
#define BK 32
#define NT (KDIM / BK)          // 64 K-tiles
#define SLOT_E (BM * BK)        // 8192 bf16 elements per A/B slot

typedef __bf16 bf16x8 __attribute__((ext_vector_type(8)));
typedef float  f32x4  __attribute__((ext_vector_type(4)));

__device__ __forceinline__ void async_load16(const void* g, void* l) {
    __builtin_amdgcn_global_load_lds(
        (const __attribute__((address_space(1))) void*)g,
        (__attribute__((address_space(3))) void*)l,
        16, 0, 0);
}

__device__ __forceinline__ float sigmoidf_(float v) {
    return 1.0f / (1.0f + __expf(-v));
}
__device__ __forceinline__ float tanhf_(float v) {
    return 1.0f - 2.0f / (__expf(2.0f * v) + 1.0f);
}

// ---------------------------------------------------------------------------
// Kernel 1: f32 -> bf16 conversion + K-concat; B side also gate-permuted.
// ---------------------------------------------------------------------------
__global__ __launch_bounds__(256) void convert_kernel(
    const float* __restrict__ x, const float* __restrict__ h,
    const float* __restrict__ U, const float* __restrict__ W,
    __hip_bfloat16* __restrict__ Acat, __hip_bfloat16* __restrict__ Bcat)
{
    const int CH_PER_MAT = (4096 * KDIM) / 8;
    int idx = blockIdx.x * blockDim.x + threadIdx.x;
    bool isB = idx >= CH_PER_MAT;
    int c = isB ? (idx - CH_PER_MAT) : idx;
    int row  = c >> 8;                 // dest row (permuted for B)
    int col  = (c & 255) << 3;
    int srow = row;
    if (isB) {
        // p = bn*256 + wn*64 + g*16 + cc  ->  orig row = g*1024 + (bn*64+wn*16+cc)
        int g  = (row >> 4) & 3;
        int j  = ((row >> 8) << 6) + (((row >> 6) & 3) << 4) + (row & 15);
        srow = g * 1024 + j;
    }
    const float* src;
    if (col < 1024) src = (isB ? U : x) + (size_t)srow * 1024 + col;
    else            src = (isB ? W : h) + (size_t)srow * 1024 + (col - 1024);
    float4 v0 = *(const float4*)(src);
    float4 v1 = *(const float4*)(src + 4);
    __hip_bfloat16 tmp[8];
    tmp[0] = __float2bfloat16(v0.x); tmp[1] = __float2bfloat16(v0.y);
    tmp[2] = __float2bfloat16(v0.z); tmp[3] = __float2bfloat16(v0.w);
    tmp[4] = __float2bfloat16(v1.x); tmp[5] = __float2bfloat16(v1.y);
    tmp[6] = __float2bfloat16(v1.z); tmp[7] = __float2bfloat16(v1.w);
    __hip_bfloat16* dst = (isB ? Bcat : Acat) + (size_t)row * KDIM + col;
    *(bf16x8*)dst = *(const bf16x8*)tmp;
}

// ---------------------------------------------------------------------------
// Kernel 2: fused bf16 GEMM + LSTM gates.
// Round-4 change: ONE barrier + ONE counted vmcnt(8) per K-tile (was 4
// barriers). Race analysis: within a tile, both MFMA halves read slot s
// and STAGE writes slot ps=(t-1)&3 (!=s), so intra-tile barriers were
// unnecessary. Every wave's ds_reads are consumed (lgkm) before it reaches
// the tile-end barrier, so the next tile's STAGE into slot (t)&3 is safe.
// ---------------------------------------------------------------------------
__global__ __launch_bounds__(512, 2) void gemm_lstm_kernel(
    const __hip_bfloat16* __restrict__ A,   // [4096][2048]
    const __hip_bfloat16* __restrict__ Bm,  // [4096][2048] gate-permuted
    const float* __restrict__ Ub,           // [4096]
    const float* __restrict__ c_prev,       // [4096][1024]
    float* __restrict__ out)                // h_t [4096][1024] ++ c_t [4096][1024]
{
    __shared__ __align__(16) __hip_bfloat16 smem[4 * 2 * SLOT_E];  // 128 KB

    const int tid  = threadIdx.x;
    const int lane = tid & 63;
    const int wid  = tid >> 6;     // 0..7
    const int wm   = wid >> 2;     // 0..1  (M half)
    const int wn   = wid & 3;      // 0..3  (N quarter)

    // XCD-aware swizzle: 256 blocks, 256 % 8 == 0 -> bijective.
    int wg  = blockIdx.x;
    int wgs = (wg & 7) * (256 / 8) + (wg >> 3);
    const int bm = wgs >> 4;
    const int bn = wgs & 15;

    const __hip_bfloat16* Ab = A  + (size_t)bm * BM * KDIM;
    const __hip_bfloat16* Bb = Bm + (size_t)bn * BN * KDIM;

    // ds_read fragment addressing (T2-swizzled).
    const int frow = lane & 15;
    const int sp8  = (((lane >> 4) ^ ((frow >> 1) & 3)) << 3);
    const int arow = wm * 128 + frow;
    const int brow = wn * 64  + frow;

    // Staging: 1024 16B-chunks/matrix/K-tile; linear LDS dest, pre-swizzled
    // global source (both-sides-or-neither rule).
    const int c0 = tid,        c1 = 512 + tid;
    const int r0 = c0 >> 2,    r1 = c1 >> 2;
    const int g0 = ((c0 & 3) ^ ((r0 >> 1) & 3)) << 3;
    const int g1 = ((c1 & 3) ^ ((r1 >> 1) & 3)) << 3;
    const size_t ga0 = (size_t)r0 * KDIM + g0;
    const size_t ga1 = (size_t)r1 * KDIM + g1;
    const int l0 = c0 << 3,    l1 = c1 << 3;

    f32x4 acc[8][4] = {};

#define STAGE_A(kt, slot) do { \
    int _ko = (kt) * BK; unsigned _b = (unsigned)((slot) * 2 + 0) * SLOT_E; \
    async_load16(Ab + ga0 + _ko, &smem[_b + l0]); \
    async_load16(Ab + ga1 + _ko, &smem[_b + l1]); } while (0)
#define STAGE_B(kt, slot) do { \
    int _ko = (kt) * BK; unsigned _b = (unsigned)((slot) * 2 + 1) * SLOT_E; \
    async_load16(Bb + ga0 + _ko, &smem[_b + l0]); \
    async_load16(Bb + ga1 + _ko, &smem[_b + l1]); } while (0)

    // ---- prologue: stage K0..K2; vmcnt(8) completes K0 (4 oldest of 12) ----
    STAGE_A(0, 0); STAGE_B(0, 0);
    STAGE_A(1, 1); STAGE_B(1, 1);
    STAGE_A(2, 2); STAGE_B(2, 2);
    asm volatile("s_waitcnt vmcnt(8)" ::: "memory");
    __builtin_amdgcn_s_barrier();

    for (int t = 0; t < NT; ++t) {
        const int slot = t & 3;
        const unsigned ab = (unsigned)(slot * 2 + 0) * SLOT_E;
        const unsigned bb = (unsigned)(slot * 2 + 1) * SLOT_E;
        int tp = t + 3; if (tp > NT - 1) tp = NT - 1;   // clamp keeps vmcnt exact
        const int ps = (t + 3) & 3;

        // issue next-tile staging ASAP (writes slot ps != slot -> no race)
        STAGE_A(tp, ps);
        STAGE_B(tp, ps);

        // fragments for MFMA half 1 (m=0..3) + B (shared)
        bf16x8 ar[4], br[4];
#pragma unroll
        for (int m = 0; m < 4; ++m)
            ar[m] = *(const bf16x8*)&smem[ab + (unsigned)((arow + m * 16) * BK) + sp8];
#pragma unroll
        for (int n = 0; n < 4; ++n)
            br[n] = *(const bf16x8*)&smem[bb + (unsigned)((brow + n * 16) * BK) + sp8];

        __builtin_amdgcn_s_setprio(1);
#pragma unroll
        for (int m = 0; m < 4; ++m)
#pragma unroll
            for (int n = 0; n < 4; ++n)
                acc[m][n] = __builtin_amdgcn_mfma_f32_16x16x32_bf16(ar[m], br[n], acc[m][n], 0, 0, 0);
        __builtin_amdgcn_s_setprio(0);

        // fragments for MFMA half 2 (m=4..7), reads overlap half-1 MFMA drain
        bf16x8 ar2[4];
#pragma unroll
        for (int m = 0; m < 4; ++m)
            ar2[m] = *(const bf16x8*)&smem[ab + (unsigned)((arow + 64 + m * 16) * BK) + sp8];

        __builtin_amdgcn_s_setprio(1);
#pragma unroll
        for (int m = 0; m < 4; ++m)
#pragma unroll
            for (int n = 0; n < 4; ++n)
                acc[m + 4][n] = __builtin_amdgcn_mfma_f32_16x16x32_bf16(ar2[m], br[n], acc[m + 4][n], 0, 0, 0);
        __builtin_amdgcn_s_setprio(0);

        // counted wait: K(t+1) fully staged (issued 2 tiles ago);
        // K(t+2),K(t+3) stay in flight. ONE barrier per tile.
        asm volatile("s_waitcnt vmcnt(8)" ::: "memory");
        __builtin_amdgcn_s_barrier();
    }
#undef STAGE_A
#undef STAGE_B

    // ---- fused epilogue: gates lane-local thanks to B permutation ----
    const int j = bn * 64 + wn * 16 + (lane & 15);
    const float bf_ = Ub[j];
    const float bi_ = Ub[1024 + j];
    const float bo_ = Ub[2048 + j];
    const float bg_ = Ub[3072 + j];
    const int row0 = bm * BM + wm * 128 + ((lane >> 4) << 2);

    // batch all c_prev loads first (hide latency), then math + stores
    float cp[8][4];
#pragma unroll
    for (int m = 0; m < 8; ++m)
#pragma unroll
        for (int r = 0; r < 4; ++r)
            cp[m][r] = c_prev[(size_t)(row0 + m * 16 + r) * HID + j];

#pragma unroll
    for (int m = 0; m < 8; ++m) {
#pragma unroll
        for (int r = 0; r < 4; ++r) {
            const int row = row0 + m * 16 + r;
            const float f  = sigmoidf_(acc[m][0][r] + bf_);
            const float it = sigmoidf_(acc[m][1][r] + bi_);
            const float o  = sigmoidf_(acc[m][2][r] + bo_);
            const float gg = tanhf_(acc[m][3][r] + bg_);
            const float cv = f * cp[m][r] + it * gg;
            const float hv = o * tanhf_(cv);
            out[(size_t)row * HID + j] = hv;
            out[(size_t)BATCH * HID + (size_t)row * HID + j] = cv;
        }
    }
}

// ---------------------------------------------------------------------------
extern "C" void kernel_launch(void* const* d_in, const int* in_sizes, int n_in,
                              void* d_out, int out_size, void* d_ws, size_t ws_size,
                              hipStream_t stream) {
    const float* x      = (const float*)d_in[0];
    const float* h_prev = (const float*)d_in[1];
    const float* c_prev = (const float*)d_in[2];
    const float* U_w    = (const float*)d_in[3];
    const float* U_b    = (const float*)d_in[4];
    const float* W_w    = (const float*)d_in[5];
    float* out = (float*)d_out;

    char* ws = (char*)d_ws;
    __hip_bfloat16* Acat = (__hip_bfloat16*)ws;                      // 16 MB
    __hip_bfloat16* Bcat = (__hip_bfloat16*)(ws + (16u << 20));      // 16 MB

    convert_kernel<<<8192, 256, 0, stream>>>(x, h_prev, U_w, W_w, Acat, Bcat);
    gemm_lstm_kernel<<<256, 512, 0, stream>>>(Acat, Bcat, U_b, c_prev, out);
}

// Round 5
// 88.685 us; speedup vs baseline: 1.0321x; 1.0321x over previous
//
#include <hip/hip_runtime.h>
#include <hip/hip_bf16.h>

// Problem: B=4096, IN=1024, H=1024.
// pre = x@U^T + h@W^T + Ub -> gates -> h_t, c_t   (fused after convert)
// GEMM: M=4096 (batch), N=4096 (4H permuted), K=2048 (IN+H concat)
//
// B-permutation: permuted column p = bn*256 + wn*64 + g*16 + c corresponds to
// gate g (f,i,o,g), hidden j = bn*64 + wn*16 + c. With the verified C/D
// layout (col = lane&15), wave fragment n == gate n at the SAME lane (same j),
// so the LSTM gate math is lane-local in the GEMM epilogue.

#define BATCH 4096
#define HID   1024
#define KDIM  2048

// 256x256 tile, BK=32, 4-slot LDS ring, 8 waves (2Mx4N), 512 threads.
#define BM 256
#define BN 256
#define BK 32
#define NT (KDIM / BK)          // 64 K-tiles
#define SLOT_E (BM * BK)        // 8192 bf16 elements per A/B slot

typedef __bf16 bf16x8 __attribute__((ext_vector_type(8)));
typedef float  f32x4  __attribute__((ext_vector_type(4)));

__device__ __forceinline__ void async_load16(const void* g, void* l) {
    __builtin_amdgcn_global_load_lds(
        (const __attribute__((address_space(1))) void*)g,
        (__attribute__((address_space(3))) void*)l,
        16, 0, 0);
}

__device__ __forceinline__ float sigmoidf_(float v) {
    return 1.0f / (1.0f + __expf(-v));
}
__device__ __forceinline__ float tanhf_(float v) {
    return 1.0f - 2.0f / (__expf(2.0f * v) + 1.0f);
}

// ---------------------------------------------------------------------------
// Kernel 1: f32 -> bf16 conversion + K-concat; B side also gate-permuted.
// ---------------------------------------------------------------------------
__global__ __launch_bounds__(256) void convert_kernel(
    const float* __restrict__ x, const float* __restrict__ h,
    const float* __restrict__ U, const float* __restrict__ W,
    __hip_bfloat16* __restrict__ Acat, __hip_bfloat16* __restrict__ Bcat)
{
    const int CH_PER_MAT = (4096 * KDIM) / 8;
    int idx = blockIdx.x * blockDim.x + threadIdx.x;
    bool isB = idx >= CH_PER_MAT;
    int c = isB ? (idx - CH_PER_MAT) : idx;
    int row  = c >> 8;                 // dest row (permuted for B)
    int col  = (c & 255) << 3;
    int srow = row;
    if (isB) {
        // p = bn*256 + wn*64 + g*16 + cc  ->  orig row = g*1024 + (bn*64+wn*16+cc)
        int g  = (row >> 4) & 3;
        int j  = ((row >> 8) << 6) + (((row >> 6) & 3) << 4) + (row & 15);
        srow = g * 1024 + j;
    }
    const float* src;
    if (col < 1024) src = (isB ? U : x) + (size_t)srow * 1024 + col;
    else            src = (isB ? W : h) + (size_t)srow * 1024 + (col - 1024);
    float4 v0 = *(const float4*)(src);
    float4 v1 = *(const float4*)(src + 4);
    __hip_bfloat16 tmp[8];
    tmp[0] = __float2bfloat16(v0.x); tmp[1] = __float2bfloat16(v0.y);
    tmp[2] = __float2bfloat16(v0.z); tmp[3] = __float2bfloat16(v0.w);
    tmp[4] = __float2bfloat16(v1.x); tmp[5] = __float2bfloat16(v1.y);
    tmp[6] = __float2bfloat16(v1.z); tmp[7] = __float2bfloat16(v1.w);
    __hip_bfloat16* dst = (isB ? Bcat : Acat) + (size_t)row * KDIM + col;
    *(bf16x8*)dst = *(const bf16x8*)tmp;
}

// ---------------------------------------------------------------------------
// Kernel 2: fused bf16 GEMM + LSTM gates.
// Round-5 changes:
//  (a) __launch_bounds__(512,1): grid==CU count means the 2nd block slot was
//      never fillable; the (512,2) bound was capping VGPRs at 128 for nothing.
//  (b) Cross-barrier ds_read pipeline: after vmcnt(8) lands K(t+1), issue all
//      12 ds_reads for tile t+1 BEFORE the bottom barrier; the MFMAs of tile
//      t+1 then start with operands already (nearly) in registers.
//      Race-free: slot (t+1)&3 is next written by body t+2's STAGE, which is
//      two barriers after the reads are issued and one barrier after they are
//      consumed by tile t+1's MFMAs.
// ---------------------------------------------------------------------------
__global__ __launch_bounds__(512, 1) void gemm_lstm_kernel(
    const __hip_bfloat16* __restrict__ A,   // [4096][2048]
    const __hip_bfloat16* __restrict__ Bm,  // [4096][2048] gate-permuted
    const float* __restrict__ Ub,           // [4096]
    const float* __restrict__ c_prev,       // [4096][1024]
    float* __restrict__ out)                // h_t [4096][1024] ++ c_t [4096][1024]
{
    __shared__ __align__(16) __hip_bfloat16 smem[4 * 2 * SLOT_E];  // 128 KB

    const int tid  = threadIdx.x;
    const int lane = tid & 63;
    const int wid  = tid >> 6;     // 0..7
    const int wm   = wid >> 2;     // 0..1  (M half)
    const int wn   = wid & 3;      // 0..3  (N quarter)

    // XCD-aware swizzle: 256 blocks, 256 % 8 == 0 -> bijective.
    int wg  = blockIdx.x;
    int wgs = (wg & 7) * (256 / 8) + (wg >> 3);
    const int bm = wgs >> 4;
    const int bn = wgs & 15;

    const __hip_bfloat16* Ab = A  + (size_t)bm * BM * KDIM;
    const __hip_bfloat16* Bb = Bm + (size_t)bn * BN * KDIM;

    // ds_read fragment addressing (T2-swizzled).
    const int frow = lane & 15;
    const int sp8  = (((lane >> 4) ^ ((frow >> 1) & 3)) << 3);
    const int arow = wm * 128 + frow;
    const int brow = wn * 64  + frow;

    // Staging: 1024 16B-chunks/matrix/K-tile; linear LDS dest, pre-swizzled
    // global source (both-sides-or-neither rule).
    const int c0 = tid,        c1 = 512 + tid;
    const int r0 = c0 >> 2,    r1 = c1 >> 2;
    const int g0 = ((c0 & 3) ^ ((r0 >> 1) & 3)) << 3;
    const int g1 = ((c1 & 3) ^ ((r1 >> 1) & 3)) << 3;
    const size_t ga0 = (size_t)r0 * KDIM + g0;
    const size_t ga1 = (size_t)r1 * KDIM + g1;
    const int l0 = c0 << 3,    l1 = c1 << 3;

    f32x4 acc[8][4] = {};
    bf16x8 ar[4], ar2[4], br[4];

#define STAGE_A(kt, slot) do { \
    int _ko = (kt) * BK; unsigned _b = (unsigned)((slot) * 2 + 0) * SLOT_E; \
    async_load16(Ab + ga0 + _ko, &smem[_b + l0]); \
    async_load16(Ab + ga1 + _ko, &smem[_b + l1]); } while (0)
#define STAGE_B(kt, slot) do { \
    int _ko = (kt) * BK; unsigned _b = (unsigned)((slot) * 2 + 1) * SLOT_E; \
    async_load16(Bb + ga0 + _ko, &smem[_b + l0]); \
    async_load16(Bb + ga1 + _ko, &smem[_b + l1]); } while (0)

    // prefetch all 12 fragments of K-tile kt (data already landed in LDS)
#define PREFETCH(kt) do { \
    const unsigned _ab = (unsigned)(((kt) & 3) * 2 + 0) * SLOT_E; \
    const unsigned _bb = (unsigned)(((kt) & 3) * 2 + 1) * SLOT_E; \
    _Pragma("unroll") \
    for (int m = 0; m < 4; ++m) \
        ar[m]  = *(const bf16x8*)&smem[_ab + (unsigned)((arow + m * 16) * BK) + sp8]; \
    _Pragma("unroll") \
    for (int m = 0; m < 4; ++m) \
        ar2[m] = *(const bf16x8*)&smem[_ab + (unsigned)((arow + 64 + m * 16) * BK) + sp8]; \
    _Pragma("unroll") \
    for (int n = 0; n < 4; ++n) \
        br[n]  = *(const bf16x8*)&smem[_bb + (unsigned)((brow + n * 16) * BK) + sp8]; \
    } while (0)

    // ---- prologue: stage K0..K2; vmcnt(8) completes K0 (4 oldest of 12) ----
    STAGE_A(0, 0); STAGE_B(0, 0);
    STAGE_A(1, 1); STAGE_B(1, 1);
    STAGE_A(2, 2); STAGE_B(2, 2);
    asm volatile("s_waitcnt vmcnt(8)" ::: "memory");
    __builtin_amdgcn_s_barrier();
    PREFETCH(0);

    for (int t = 0; t < NT; ++t) {
        int tp = t + 3; if (tp > NT - 1) tp = NT - 1;   // clamp keeps vmcnt exact
        const int ps = (t + 3) & 3;

        // stage K(t+3) into slot ps=(t-1)&3 (readers finished before the
        // barrier we just crossed -> no race)
        STAGE_A(tp, ps);
        STAGE_B(tp, ps);

        // MFMAs: operands prefetched across the barrier
        __builtin_amdgcn_s_setprio(1);
#pragma unroll
        for (int m = 0; m < 4; ++m)
#pragma unroll
            for (int n = 0; n < 4; ++n)
                acc[m][n] = __builtin_amdgcn_mfma_f32_16x16x32_bf16(ar[m], br[n], acc[m][n], 0, 0, 0);
#pragma unroll
        for (int m = 0; m < 4; ++m)
#pragma unroll
            for (int n = 0; n < 4; ++n)
                acc[m + 4][n] = __builtin_amdgcn_mfma_f32_16x16x32_bf16(ar2[m], br[n], acc[m + 4][n], 0, 0, 0);
        __builtin_amdgcn_s_setprio(0);

        // counted wait: K(t+1) fully staged (issued 2 tiles ago);
        // K(t+2),K(t+3) stay in flight.
        asm volatile("s_waitcnt vmcnt(8)" ::: "memory");
        // prefetch next tile's fragments BEFORE the barrier (t=63: re-read
        // slot 3 -> landed data, values unused)
        int tn = (t + 1 < NT) ? (t + 1) : (NT - 1);
        PREFETCH(tn);
        __builtin_amdgcn_sched_barrier(0);   // keep prefetch above the barrier
        __builtin_amdgcn_s_barrier();
    }
#undef STAGE_A
#undef STAGE_B
#undef PREFETCH

    // ---- fused epilogue: gates lane-local thanks to B permutation ----
    const int j = bn * 64 + wn * 16 + (lane & 15);
    const float bf_ = Ub[j];
    const float bi_ = Ub[1024 + j];
    const float bo_ = Ub[2048 + j];
    const float bg_ = Ub[3072 + j];
    const int row0 = bm * BM + wm * 128 + ((lane >> 4) << 2);

    // batch all c_prev loads first (hide latency), then math + stores
    float cp[8][4];
#pragma unroll
    for (int m = 0; m < 8; ++m)
#pragma unroll
        for (int r = 0; r < 4; ++r)
            cp[m][r] = c_prev[(size_t)(row0 + m * 16 + r) * HID + j];

#pragma unroll
    for (int m = 0; m < 8; ++m) {
#pragma unroll
        for (int r = 0; r < 4; ++r) {
            const int row = row0 + m * 16 + r;
            const float f  = sigmoidf_(acc[m][0][r] + bf_);
            const float it = sigmoidf_(acc[m][1][r] + bi_);
            const float o  = sigmoidf_(acc[m][2][r] + bo_);
            const float gg = tanhf_(acc[m][3][r] + bg_);
            const float cv = f * cp[m][r] + it * gg;
            const float hv = o * tanhf_(cv);
            out[(size_t)row * HID + j] = hv;
            out[(size_t)BATCH * HID + (size_t)row * HID + j] = cv;
        }
    }
}

// ---------------------------------------------------------------------------
extern "C" void kernel_launch(void* const* d_in, const int* in_sizes, int n_in,
                              void* d_out, int out_size, void* d_ws, size_t ws_size,
                              hipStream_t stream) {
    const float* x      = (const float*)d_in[0];
    const float* h_prev = (const float*)d_in[1];
    const float* c_prev = (const float*)d_in[2];
    const float* U_w    = (const float*)d_in[3];
    const float* U_b    = (const float*)d_in[4];
    const float* W_w    = (const float*)d_in[5];
    float* out = (float*)d_out;

    char* ws = (char*)d_ws;
    __hip_bfloat16* Acat = (__hip_bfloat16*)ws;                      // 16 MB
    __hip_bfloat16* Bcat = (__hip_bfloat16*)(ws + (16u << 20));      // 16 MB

    convert_kernel<<<8192, 256, 0, stream>>>(x, h_prev, U_w, W_w, Acat, Bcat);
    gemm_lstm_kernel<<<256, 512, 0, stream>>>(Acat, Bcat, U_b, c_prev, out);
}

// Round 6
// 88.301 us; speedup vs baseline: 1.0366x; 1.0044x over previous
//
#include <hip/hip_runtime.h>
#include <hip/hip_bf16.h>

// Problem: B=4096, IN=1024, H=1024.
// pre = x@U^T + h@W^T + Ub -> gates -> h_t, c_t   (fused after convert)
// GEMM: M=4096 (batch), N=4096 (4H permuted), K=2048 (IN+H concat)
//
// B-permutation: permuted column p = bn*256 + wn*64 + g*16 + c corresponds to
// gate g (f,i,o,g), hidden j = bn*64 + wn*16 + c. With the verified C/D
// layout (col = lane&15), wave fragment n == gate n at the SAME lane (same j),
// so the LSTM gate math is lane-local in the GEMM epilogue.

#define BATCH 4096
#define HID   1024
#define KDIM  2048

// 256x256 tile, BK=32, 4-slot LDS ring, 8 waves (2Mx4N), 512 threads.
#define BM 256
#define BN 256
#define BK 32
#define NT (KDIM / BK)          // 64 K-tiles
#define SLOT_E (BM * BK)        // 8192 bf16 elements per A/B slot

typedef __bf16 bf16x8 __attribute__((ext_vector_type(8)));
typedef float  f32x4  __attribute__((ext_vector_type(4)));

__device__ __forceinline__ void async_load16(const void* g, void* l) {
    __builtin_amdgcn_global_load_lds(
        (const __attribute__((address_space(1))) void*)g,
        (__attribute__((address_space(3))) void*)l,
        16, 0, 0);
}

__device__ __forceinline__ float sigmoidf_(float v) {
    return 1.0f / (1.0f + __expf(-v));
}
__device__ __forceinline__ float tanhf_(float v) {
    return 1.0f - 2.0f / (__expf(2.0f * v) + 1.0f);
}

// ---------------------------------------------------------------------------
// Kernel 1: f32 -> bf16 conversion + K-concat; B side also gate-permuted.
// ---------------------------------------------------------------------------
__global__ __launch_bounds__(256) void convert_kernel(
    const float* __restrict__ x, const float* __restrict__ h,
    const float* __restrict__ U, const float* __restrict__ W,
    __hip_bfloat16* __restrict__ Acat, __hip_bfloat16* __restrict__ Bcat)
{
    const int CH_PER_MAT = (4096 * KDIM) / 8;
    int idx = blockIdx.x * blockDim.x + threadIdx.x;
    bool isB = idx >= CH_PER_MAT;
    int c = isB ? (idx - CH_PER_MAT) : idx;
    int row  = c >> 8;                 // dest row (permuted for B)
    int col  = (c & 255) << 3;
    int srow = row;
    if (isB) {
        // p = bn*256 + wn*64 + g*16 + cc  ->  orig row = g*1024 + (bn*64+wn*16+cc)
        int g  = (row >> 4) & 3;
        int j  = ((row >> 8) << 6) + (((row >> 6) & 3) << 4) + (row & 15);
        srow = g * 1024 + j;
    }
    const float* src;
    if (col < 1024) src = (isB ? U : x) + (size_t)srow * 1024 + col;
    else            src = (isB ? W : h) + (size_t)srow * 1024 + (col - 1024);
    float4 v0 = *(const float4*)(src);
    float4 v1 = *(const float4*)(src + 4);
    __hip_bfloat16 tmp[8];
    tmp[0] = __float2bfloat16(v0.x); tmp[1] = __float2bfloat16(v0.y);
    tmp[2] = __float2bfloat16(v0.z); tmp[3] = __float2bfloat16(v0.w);
    tmp[4] = __float2bfloat16(v1.x); tmp[5] = __float2bfloat16(v1.y);
    tmp[6] = __float2bfloat16(v1.z); tmp[7] = __float2bfloat16(v1.w);
    __hip_bfloat16* dst = (isB ? Bcat : Acat) + (size_t)row * KDIM + col;
    *(bf16x8*)dst = *(const bf16x8*)tmp;
}

// ---------------------------------------------------------------------------
// Kernel 2: fused bf16 GEMM + LSTM gates.
// Round-6 change: fragment-register DOUBLE-BUFFERING (named sets A/B,
// 2 tiles per loop body — rule #20 safe) + counted wait moved to TOP of
// each tile body. Tile body:
//   STAGE K(t+3) -> vmcnt(8) [K(t+1) landed] -> PREFETCH(t+1) into OTHER
//   frag set (no WAR vs this tile's MFMAs) -> 32 MFMA on current set ->
//   s_barrier.
// The 12 ds_reads now have no dependency on the MFMA stream and their
// data-wait is already satisfied, so they overlap the ~1242-cyc MFMA block
// instead of serializing after it.
// Race-freedom (same ring invariants as rounds 2-5): slot s is restaged
// only 2 barriers after its ds_reads issue and 1 barrier after their data
// is consumed (lgkm-forced by the consuming MFMAs before the barrier).
// ---------------------------------------------------------------------------
__global__ __launch_bounds__(512, 1) void gemm_lstm_kernel(
    const __hip_bfloat16* __restrict__ A,   // [4096][2048]
    const __hip_bfloat16* __restrict__ Bm,  // [4096][2048] gate-permuted
    const float* __restrict__ Ub,           // [4096]
    const float* __restrict__ c_prev,       // [4096][1024]
    float* __restrict__ out)                // h_t [4096][1024] ++ c_t [4096][1024]
{
    __shared__ __align__(16) __hip_bfloat16 smem[4 * 2 * SLOT_E];  // 128 KB

    const int tid  = threadIdx.x;
    const int lane = tid & 63;
    const int wid  = tid >> 6;     // 0..7
    const int wm   = wid >> 2;     // 0..1  (M half)
    const int wn   = wid & 3;      // 0..3  (N quarter)

    // XCD-aware swizzle: 256 blocks, 256 % 8 == 0 -> bijective.
    int wg  = blockIdx.x;
    int wgs = (wg & 7) * (256 / 8) + (wg >> 3);
    const int bm = wgs >> 4;
    const int bn = wgs & 15;

    const __hip_bfloat16* Ab = A  + (size_t)bm * BM * KDIM;
    const __hip_bfloat16* Bb = Bm + (size_t)bn * BN * KDIM;

    // ds_read fragment addressing (T2-swizzled).
    const int frow = lane & 15;
    const int sp8  = (((lane >> 4) ^ ((frow >> 1) & 3)) << 3);
    const int arow = wm * 128 + frow;
    const int brow = wn * 64  + frow;

    // Staging: 1024 16B-chunks/matrix/K-tile; linear LDS dest, pre-swizzled
    // global source (both-sides-or-neither rule).
    const int c0 = tid,        c1 = 512 + tid;
    const int r0 = c0 >> 2,    r1 = c1 >> 2;
    const int g0 = ((c0 & 3) ^ ((r0 >> 1) & 3)) << 3;
    const int g1 = ((c1 & 3) ^ ((r1 >> 1) & 3)) << 3;
    const size_t ga0 = (size_t)r0 * KDIM + g0;
    const size_t ga1 = (size_t)r1 * KDIM + g1;
    const int l0 = c0 << 3,    l1 = c1 << 3;

    f32x4 acc[8][4] = {};
    // two named fragment sets (ping-pong; never runtime-indexed)
    bf16x8 arA[4], ar2A[4], brA[4];
    bf16x8 arB[4], ar2B[4], brB[4];

#define STAGE_A(kt, slot) do { \
    int _ko = (kt) * BK; unsigned _b = (unsigned)((slot) * 2 + 0) * SLOT_E; \
    async_load16(Ab + ga0 + _ko, &smem[_b + l0]); \
    async_load16(Ab + ga1 + _ko, &smem[_b + l1]); } while (0)
#define STAGE_B(kt, slot) do { \
    int _ko = (kt) * BK; unsigned _b = (unsigned)((slot) * 2 + 1) * SLOT_E; \
    async_load16(Bb + ga0 + _ko, &smem[_b + l0]); \
    async_load16(Bb + ga1 + _ko, &smem[_b + l1]); } while (0)

    // prefetch all 12 fragments of K-tile kt into the named set (data landed)
#define PREFETCH(kt, AR, AR2, BR) do { \
    const unsigned _ab = (unsigned)(((kt) & 3) * 2 + 0) * SLOT_E; \
    const unsigned _bb = (unsigned)(((kt) & 3) * 2 + 1) * SLOT_E; \
    _Pragma("unroll") \
    for (int m = 0; m < 4; ++m) \
        AR[m]  = *(const bf16x8*)&smem[_ab + (unsigned)((arow + m * 16) * BK) + sp8]; \
    _Pragma("unroll") \
    for (int m = 0; m < 4; ++m) \
        AR2[m] = *(const bf16x8*)&smem[_ab + (unsigned)((arow + 64 + m * 16) * BK) + sp8]; \
    _Pragma("unroll") \
    for (int n = 0; n < 4; ++n) \
        BR[n]  = *(const bf16x8*)&smem[_bb + (unsigned)((brow + n * 16) * BK) + sp8]; \
    } while (0)

#define MFMA_TILE(AR, AR2, BR) do { \
    __builtin_amdgcn_s_setprio(1); \
    _Pragma("unroll") \
    for (int m = 0; m < 4; ++m) \
        _Pragma("unroll") \
        for (int n = 0; n < 4; ++n) \
            acc[m][n] = __builtin_amdgcn_mfma_f32_16x16x32_bf16(AR[m], BR[n], acc[m][n], 0, 0, 0); \
    _Pragma("unroll") \
    for (int m = 0; m < 4; ++m) \
        _Pragma("unroll") \
        for (int n = 0; n < 4; ++n) \
            acc[m + 4][n] = __builtin_amdgcn_mfma_f32_16x16x32_bf16(AR2[m], BR[n], acc[m + 4][n], 0, 0, 0); \
    __builtin_amdgcn_s_setprio(0); \
    } while (0)

    // ---- prologue: stage K0..K2; vmcnt(8) completes K0 (4 oldest of 12) ----
    STAGE_A(0, 0); STAGE_B(0, 0);
    STAGE_A(1, 1); STAGE_B(1, 1);
    STAGE_A(2, 2); STAGE_B(2, 2);
    asm volatile("s_waitcnt vmcnt(8)" ::: "memory");
    __builtin_amdgcn_s_barrier();
    PREFETCH(0, arA, ar2A, brA);

#pragma unroll 1
    for (int i = 0; i < NT / 2; ++i) {
        const int t0 = 2 * i, t1 = 2 * i + 1;
        {   // ---- tile t0: consume set A, prefetch set B for t1 ----
            int tp = t0 + 3; if (tp > NT - 1) tp = NT - 1;
            const int ps = (t0 + 3) & 3;
            STAGE_A(tp, ps);
            STAGE_B(tp, ps);
            asm volatile("s_waitcnt vmcnt(8)" ::: "memory");  // K(t0+1) landed
            PREFETCH(t1, arB, ar2B, brB);     // t1 <= 63 always
            MFMA_TILE(arA, ar2A, brA);
            __builtin_amdgcn_s_barrier();
        }
        {   // ---- tile t1: consume set B, prefetch set A for t1+1 ----
            int tp = t1 + 3; if (tp > NT - 1) tp = NT - 1;
            const int ps = (t1 + 3) & 3;
            STAGE_A(tp, ps);
            STAGE_B(tp, ps);
            asm volatile("s_waitcnt vmcnt(8)" ::: "memory");  // K(t1+1) landed
            int tn = (t1 + 1 <= NT - 1) ? (t1 + 1) : (NT - 1); // i=31: re-read K63 (unused)
            PREFETCH(tn, arA, ar2A, brA);
            MFMA_TILE(arB, ar2B, brB);
            __builtin_amdgcn_s_barrier();
        }
    }
#undef STAGE_A
#undef STAGE_B
#undef PREFETCH
#undef MFMA_TILE

    // ---- fused epilogue: gates lane-local thanks to B permutation ----
    const int j = bn * 64 + wn * 16 + (lane & 15);
    const float bf_ = Ub[j];
    const float bi_ = Ub[1024 + j];
    const float bo_ = Ub[2048 + j];
    const float bg_ = Ub[3072 + j];
    const int row0 = bm * BM + wm * 128 + ((lane >> 4) << 2);

    // batch all c_prev loads first (hide latency), then math + stores
    float cp[8][4];
#pragma unroll
    for (int m = 0; m < 8; ++m)
#pragma unroll
        for (int r = 0; r < 4; ++r)
            cp[m][r] = c_prev[(size_t)(row0 + m * 16 + r) * HID + j];

#pragma unroll
    for (int m = 0; m < 8; ++m) {
#pragma unroll
        for (int r = 0; r < 4; ++r) {
            const int row = row0 + m * 16 + r;
            const float f  = sigmoidf_(acc[m][0][r] + bf_);
            const float it = sigmoidf_(acc[m][1][r] + bi_);
            const float o  = sigmoidf_(acc[m][2][r] + bo_);
            const float gg = tanhf_(acc[m][3][r] + bg_);
            const float cv = f * cp[m][r] + it * gg;
            const float hv = o * tanhf_(cv);
            out[(size_t)row * HID + j] = hv;
            out[(size_t)BATCH * HID + (size_t)row * HID + j] = cv;
        }
    }
}

// ---------------------------------------------------------------------------
extern "C" void kernel_launch(void* const* d_in, const int* in_sizes, int n_in,
                              void* d_out, int out_size, void* d_ws, size_t ws_size,
                              hipStream_t stream) {
    const float* x      = (const float*)d_in[0];
    const float* h_prev = (const float*)d_in[1];
    const float* c_prev = (const float*)d_in[2];
    const float* U_w    = (const float*)d_in[3];
    const float* U_b    = (const float*)d_in[4];
    const float* W_w    = (const float*)d_in[5];
    float* out = (float*)d_out;

    char* ws = (char*)d_ws;
    __hip_bfloat16* Acat = (__hip_bfloat16*)ws;                      // 16 MB
    __hip_bfloat16* Bcat = (__hip_bfloat16*)(ws + (16u << 20));      // 16 MB

    convert_kernel<<<8192, 256, 0, stream>>>(x, h_prev, U_w, W_w, Acat, Bcat);
    gemm_lstm_kernel<<<256, 512, 0, stream>>>(Acat, Bcat, U_b, c_prev, out);
}